// Round 1
// 178.273 us; speedup vs baseline: 1.0670x; 1.0670x over previous
//
#include <hip/hip_runtime.h>
#include <stdint.h>

// ---------------------------------------------------------------------------
// HardBinaryConv, algebraic form.
//   sign(w) = 1 - 2*[w <= 0]   (reference: 2*(w>0)-1)
//   y[n,o,h,w] = scale[o] * T[n,h,w]
//              - 2*scale[o] * sum_{(i,r,s): w[o,i,r,s]<=0} x[n,i,h+r-1,w+s-1]
//   T[n,h,w]   = sum_{r,s} U[n,h+r-1,w+s-1]   (3x3 box, zero-pad)
//   U[n,h,w]   = sum_i x[n,i,h,w]             (channel sum)
// Correction set is empty for uniform*1e-3 weights but handled exactly.
// Traffic floor: read x (103 MB) + write y (103 MB) ~= 31 us at 6.7 TB/s.
// This version: 3 launches (wprep fused into stage 1), NT hints on the two
// 103-MB streams, boxsum at 448 blocks for occupancy.
// ---------------------------------------------------------------------------

typedef float f32x4 __attribute__((ext_vector_type(4)));

// Stage 1, role A (blocks 0..1567): per-16-channel-group partial channel sums.
// u16 layout: [n][g=16][784] f32x4.  401408 threads.
// Stage 1, role B (blocks 1568..1823): scale[o] = mean|w[o]| + sparse list of
// non-positive weights (block o-1568 owns nneg[o]; no global pre-zero needed).
__global__ __launch_bounds__(256) void stage1(const float* __restrict__ x,
                                              f32x4* __restrict__ u16,
                                              const float* __restrict__ w,
                                              float* __restrict__ scale,
                                              int* __restrict__ nneg,
                                              int* __restrict__ negidx) {
    __shared__ float red[4];
    __shared__ int cnt;
    if (blockIdx.x < 1568) {
        const int id  = blockIdx.x * 256 + threadIdx.x;
        const int n   = id / 12544;          // 12544 = 16*784
        const int rem = id - n * 12544;
        const int g   = rem / 784;
        const int hw4 = rem - g * 784;
        const f32x4* xp =
            (const f32x4*)(x + (size_t)(n * 256 + g * 16) * 3136) + hw4;
        f32x4 s = {0.f, 0.f, 0.f, 0.f};
#pragma unroll
        for (int c = 0; c < 16; ++c)         // 784 f32x4 = one 3136-elem plane
            s += __builtin_nontemporal_load(xp + c * 784);
        u16[id] = s;                         // plain store: keep in L2 for boxsum
    } else {
        const int o = blockIdx.x - 1568, i = threadIdx.x;
        if (i == 0) cnt = 0;
        __syncthreads();
        const float* wp = w + ((size_t)o * 256 + i) * 9;
        float s = 0.f;
#pragma unroll
        for (int k = 0; k < 9; ++k) {
            const float v = wp[k];
            s += fabsf(v);
            if (v <= 0.f) {                  // sign would be -1 here (rare)
                const int slot = atomicAdd(&cnt, 1);
                negidx[o * 2304 + slot] = i * 9 + k;
            }
        }
#pragma unroll
        for (int off = 32; off > 0; off >>= 1) s += __shfl_down(s, off);
        if ((i & 63) == 0) red[i >> 6] = s;
        __syncthreads();
        if (i == 0) {
            scale[o] = (red[0] + red[1] + red[2] + red[3]) * (1.0f / 2304.0f);
            nneg[o]  = cnt;
        }
    }
}

// Stage 2: reduce 16 groups + 3x3 zero-padded box filter.
// grid 448 = 32 n * 14 stripes of 4 output rows; 6 halo rows in LDS.
__global__ __launch_bounds__(256) void boxsum(const float* __restrict__ u16,
                                              float* __restrict__ T) {
    __shared__ float Us[336];                // 6 rows x 56
    const int n  = blockIdx.x / 14;
    const int h0 = (blockIdx.x - n * 14) * 4;
    const float* base = u16 + (size_t)n * 16 * 3136;
    for (int idx = threadIdx.x; idx < 336; idx += 256) {
        const int lr = idx / 56, col = idx - lr * 56;
        const int h = h0 - 1 + lr;
        float s = 0.f;
        if (h >= 0 && h < 56) {
            const float* bp = base + h * 56 + col;
#pragma unroll
            for (int g = 0; g < 16; ++g) s += bp[g * 3136];
        }
        Us[idx] = s;
    }
    __syncthreads();
    float* Tn = T + (size_t)n * 3136;
    for (int idx = threadIdx.x; idx < 224; idx += 256) {
        const int lr = idx / 56, w = idx - lr * 56;
        float acc = 0.f;
#pragma unroll
        for (int r = 0; r < 3; ++r) {
            const float* row = Us + (lr + r) * 56;
            if (w > 0)  acc += row[w - 1];
            acc += row[w];
            if (w < 55) acc += row[w + 1];
        }
        Tn[(h0 + lr) * 56 + w] = acc;
    }
}

// Stage 3: broadcast scale[o]*T into each (n,o) output plane (+ correction).
// grid 8192 = n*256+o (o fastest => T[n] L2-resident across 256 blocks).
// NT stores: y is written once, never re-read -> don't flush L2 with it.
__global__ __launch_bounds__(256) void yout(const float* __restrict__ T,
                                            const float* __restrict__ scale,
                                            const int* __restrict__ nneg,
                                            const int* __restrict__ negidx,
                                            const float* __restrict__ x,
                                            float* __restrict__ out) {
    const int b = blockIdx.x;
    const int o = b & 255, n = b >> 8;
    const float sc = scale[o];
    const f32x4* Tn = (const f32x4*)(T + (size_t)n * 3136);
    f32x4* op = (f32x4*)(out + ((size_t)n * 256 + o) * 3136);
    if (nneg[o] == 0) {                      // uniform fast path
#pragma unroll
        for (int j = 0; j < 4; ++j) {
            const int hw4 = threadIdx.x + j * 256;
            if (hw4 >= 784) break;           // 784 f32x4 = 3136 floats
            f32x4 v = Tn[hw4] * sc;
            __builtin_nontemporal_store(v, op + hw4);
        }
    } else {                                 // exact sparse correction (rare)
        const int nn = nneg[o];
        const float c2 = 2.f * sc;
#pragma unroll
        for (int j = 0; j < 4; ++j) {
            const int hw4 = threadIdx.x + j * 256;
            if (hw4 >= 784) break;
            f32x4 v = Tn[hw4] * sc;
            for (int q = 0; q < nn; ++q) {
                const int iof = negidx[o * 2304 + q];
                const int i = iof / 9, rs = iof - i * 9;
                const int r = rs / 3 - 1, s2 = rs - (rs / 3) * 3 - 1;
                const float* xpl = x + ((size_t)n * 256 + i) * 3136;
#pragma unroll
                for (int e = 0; e < 4; ++e) {
                    const int hw = hw4 * 4 + e;
                    const int h = hw / 56 + r, ww = hw - (hw / 56) * 56 + s2;
                    const float xv = (h >= 0 && h < 56 && ww >= 0 && ww < 56)
                                         ? xpl[h * 56 + ww] : 0.f;
                    v[e] -= c2 * xv;
                }
            }
            __builtin_nontemporal_store(v, op + hw4);
        }
    }
}

// ---------------------------------------------------------------------------
extern "C" void kernel_launch(void* const* d_in, const int* in_sizes, int n_in,
                              void* d_out, int out_size, void* d_ws, size_t ws_size,
                              hipStream_t stream) {
    const float* x = (const float*)d_in[0];   // (32,256,56,56) fp32, 103 MB
    const float* w = (const float*)d_in[1];   // (256,256,3,3) fp32, 2.4 MB
    float* out = (float*)d_out;               // (32,256,56,56) fp32, 103 MB

    char* ws = (char*)d_ws;
    size_t off = 0;
    float* u16 = (float*)(ws + off);          // 32*16*3136 fp32 = 6.4 MB
    off += (size_t)32 * 16 * 3136 * 4;
    float* T = (float*)(ws + off);            // 32*3136 fp32 = 401 KB
    off += (size_t)32 * 3136 * 4;
    float* scale = (float*)(ws + off);        // 256 fp32
    off += 256 * 4;
    int* nneg = (int*)(ws + off);             // 256 int
    off += 256 * 4;
    int* negidx = (int*)(ws + off);           // 256*2304 int = 2.4 MB

    stage1<<<dim3(1824), 256, 0, stream>>>(x, (f32x4*)u16, w, scale, nneg, negidx);
    boxsum<<<dim3(448), 256, 0, stream>>>(u16, T);
    yout<<<dim3(8192), 256, 0, stream>>>(T, scale, nneg, negidx, x, out);
}